// Round 1
// baseline (267.502 us; speedup 1.0000x reference)
//
#include <hip/hip_runtime.h>
#include <hip/hip_bf16.h>
#include <cmath>

#define NB 4
#define NM 32
#define DKc 256
#define DVc 32
#define NP 4096

using bf16x8 = __attribute__((ext_vector_type(8))) short;
using f32x4  = __attribute__((ext_vector_type(4))) float;

__device__ __forceinline__ unsigned short f2bf(float f) {
    union { float f; unsigned u; } x; x.f = f;
    unsigned r = 0x7FFFu + ((x.u >> 16) & 1u);
    return (unsigned short)((x.u + r) >> 16);
}
__device__ __forceinline__ float bflo(unsigned u) { union { unsigned u; float f; } x; x.u = u << 16; return x.f; }
__device__ __forceinline__ float bfhi(unsigned u) { union { unsigned u; float f; } x; x.u = u & 0xffff0000u; return x.f; }
__device__ __forceinline__ float bf2f(unsigned short s) { union { unsigned u; float f; } x; x.u = ((unsigned)s) << 16; return x.f; }

// src [R][C] fp32 -> dst [C][R] bf16 (per batch). C,R multiples of 64.
__global__ __launch_bounds__(256) void k_transpose_bf16(
    const float* __restrict__ src, unsigned short* __restrict__ dst,
    int R, int C, long batchStride) {
    __shared__ float tile[64][65];
    int b = blockIdx.z;
    const float* s = src + (long)b * batchStride;
    unsigned short* d = dst + (long)b * batchStride;
    int r0 = blockIdx.y * 64, c0 = blockIdx.x * 64;
    int t = threadIdx.x;
    #pragma unroll
    for (int j = 0; j < 16; ++j) {
        int i = t + 256 * j;
        int r = i >> 6, c = i & 63;
        tile[r][c] = s[(long)(r0 + r) * C + c0 + c];
    }
    __syncthreads();
    #pragma unroll
    for (int j = 0; j < 8; ++j) {
        int i = t + 256 * j;
        int row = i >> 5;   // local output row (along C)
        int pr = i & 31;    // pair index along R
        float f0 = tile[2 * pr][row];
        float f1 = tile[2 * pr + 1][row];
        unsigned pack = (unsigned)f2bf(f0) | ((unsigned)f2bf(f1) << 16);
        reinterpret_cast<unsigned*>(d)[(((long)(c0 + row) * R + r0) >> 1) + pr] = pack;
    }
}

// vproj[frame][e][p] = sum_d fm[frame][d][p] * V[d][e]
__global__ __launch_bounds__(256) void k_vproj(
    const float* __restrict__ fm, const float* __restrict__ V, float* __restrict__ vproj) {
    __shared__ float Vl[32][32];
    __shared__ float fml[32][256];
    int b = blockIdx.y, p0 = blockIdx.x * 256, t = threadIdx.x;
    #pragma unroll
    for (int j = 0; j < 4; ++j) { int i = t + 256 * j; Vl[i >> 5][i & 31] = V[i]; }
    for (int j = 0; j < 32; ++j) {
        int i = t + 256 * j;
        int dd = i >> 8, c = i & 255;
        fml[dd][c] = fm[((long)b * DVc + dd) * NP + p0 + c];
    }
    __syncthreads();
    float acc[32];
    #pragma unroll
    for (int e = 0; e < 32; ++e) acc[e] = 0.f;
    for (int dd = 0; dd < 32; ++dd) {
        float fv = fml[dd][t];
        #pragma unroll
        for (int e = 0; e < 32; ++e) acc[e] += fv * Vl[dd][e];
    }
    #pragma unroll
    for (int e = 0; e < 32; ++e) vproj[((long)b * DVc + e) * NP + p0 + t] = acc[e];
}

// out[e,p] = sum_d WT[e][d] * fcT[b][p][d]  (bf16 MFMA 16x16x32)
// mat==0 -> qT bf16 [b][p][e];  mat==1 -> kproj fp32 [b][e][p]
__global__ __launch_bounds__(256) void k_proj_gemm(
    const unsigned short* __restrict__ WTq, const unsigned short* __restrict__ WTk,
    const unsigned short* __restrict__ fcT,
    unsigned short* __restrict__ qT, float* __restrict__ kproj) {
    int t = threadIdx.x;
    int wave = t >> 6, lane = t & 63;
    int b = blockIdx.z & 3, mat = blockIdx.z >> 2;
    int e0 = blockIdx.y * 64 + wave * 16;
    int p0 = blockIdx.x * 64;
    int ln = lane & 15, quad = lane >> 4;
    const unsigned short* WT = mat ? WTk : WTq;
    const unsigned short* aptr = WT + (long)(e0 + ln) * DKc + quad * 8;
    const unsigned short* bbase = fcT + ((long)b * NP + p0 + ln) * DKc + quad * 8;
    f32x4 acc[4] = {};
    for (int kk = 0; kk < DKc; kk += 32) {
        bf16x8 a = *reinterpret_cast<const bf16x8*>(aptr + kk);
        #pragma unroll
        for (int j = 0; j < 4; ++j) {
            bf16x8 bb = *reinterpret_cast<const bf16x8*>(bbase + (long)j * 16 * DKc + kk);
            acc[j] = __builtin_amdgcn_mfma_f32_16x16x32_bf16(a, bb, acc[j], 0, 0, 0);
        }
    }
    int eb = e0 + quad * 4;
    if (mat == 0) {
        #pragma unroll
        for (int j = 0; j < 4; ++j)
            #pragma unroll
            for (int r = 0; r < 4; ++r) {
                int e = eb + r, p = p0 + j * 16 + ln;
                qT[((long)b * NP + p) * DKc + e] = f2bf(acc[j][r]);
            }
    } else {
        #pragma unroll
        for (int j = 0; j < 4; ++j)
            #pragma unroll
            for (int r = 0; r < 4; ++r) {
                int e = eb + r, p = p0 + j * 16 + ln;
                kproj[((long)b * DKc + e) * NP + p] = acc[j][r];
            }
    }
}

// scores[b][m][p] = SCALE * sum_e qT[b][p][e] * k[m][e][p]
// block: (p-tile 32, m-half). 512 threads: g=t>>5 (e-group of 16), p=t&31.
__global__ __launch_bounds__(512) void k_scores(
    const unsigned short* __restrict__ qT, const float* __restrict__ kproj,
    const float* __restrict__ kbuf, float* __restrict__ scores, float scale) {
    __shared__ float red[16][4][4][32];
    int t = threadIdx.x;
    int g = t >> 5, p = t & 31;
    int p0 = blockIdx.x * 32;
    int mg = blockIdx.y;
    float qreg[4][16];
    #pragma unroll
    for (int b = 0; b < 4; ++b) {
        const uint4* qp4 = reinterpret_cast<const uint4*>(qT + ((long)b * NP + p0 + p) * DKc + g * 16);
        uint4 u0 = qp4[0], u1 = qp4[1];
        unsigned w[8] = {u0.x, u0.y, u0.z, u0.w, u1.x, u1.y, u1.z, u1.w};
        #pragma unroll
        for (int j = 0; j < 8; ++j) { qreg[b][2 * j] = bflo(w[j]); qreg[b][2 * j + 1] = bfhi(w[j]); }
    }
    for (int c = 0; c < 4; ++c) {
        float acc[4][4];
        #pragma unroll
        for (int mi = 0; mi < 4; ++mi)
            #pragma unroll
            for (int b = 0; b < 4; ++b) acc[mi][b] = 0.f;
        #pragma unroll
        for (int mi = 0; mi < 4; ++mi) {
            int m = mg * 16 + c * 4 + mi;
            const float* kp = (m < 4 ? kproj + (long)m * DKc * NP : kbuf + (long)(m - 4) * DKc * NP)
                              + (long)(g * 16) * NP + p0 + p;
            #pragma unroll
            for (int j = 0; j < 16; ++j) {
                float kv = kp[(long)j * NP];
                acc[mi][0] += qreg[0][j] * kv;
                acc[mi][1] += qreg[1][j] * kv;
                acc[mi][2] += qreg[2][j] * kv;
                acc[mi][3] += qreg[3][j] * kv;
            }
        }
        #pragma unroll
        for (int mi = 0; mi < 4; ++mi)
            #pragma unroll
            for (int b = 0; b < 4; ++b) red[g][mi][b][p] = acc[mi][b];
        __syncthreads();
        {
            int mi = t >> 7, b = (t >> 5) & 3, pp = t & 31;
            float s = 0.f;
            #pragma unroll
            for (int gg = 0; gg < 16; ++gg) s += red[gg][mi][b][pp];
            int m = mg * 16 + c * 4 + mi;
            scores[((long)b * NM + m) * NP + p0 + pp] = scale * s;
        }
        __syncthreads();
    }
}

// softmax over w (rows of 64) + ctx + out = fm + 0.5*ctx
// block: (p-tile 128 = 2 h-rows, d-quarter). 256 threads.
__global__ __launch_bounds__(256) void k_out(
    const float* __restrict__ scores, const float* __restrict__ vproj,
    const float* __restrict__ vbuf, const float* __restrict__ fm,
    float* __restrict__ out) {
    __shared__ unsigned short attn[128][130];
    int t = threadIdx.x;
    int p0 = blockIdx.x * 128;
    int dq = blockIdx.y;
    {   // phase 1: one softmax row (64 w's) per thread
        int b = t >> 6, mrow = (t >> 1) & 31, hs = t & 1;
        const f32x4* s4 = reinterpret_cast<const f32x4*>(scores + ((long)b * NM + mrow) * NP + p0 + hs * 64);
        f32x4 v[16];
        #pragma unroll
        for (int j = 0; j < 16; ++j) v[j] = s4[j];
        float mx = v[0][0];
        #pragma unroll
        for (int j = 0; j < 16; ++j)
            #pragma unroll
            for (int k = 0; k < 4; ++k) mx = fmaxf(mx, v[j][k]);
        float sum = 0.f;
        #pragma unroll
        for (int j = 0; j < 16; ++j)
            #pragma unroll
            for (int k = 0; k < 4; ++k) { float e = __expf(v[j][k] - mx); v[j][k] = e; sum += e; }
        float inv = 1.f / sum;
        unsigned short* arow = &attn[(b << 5) | mrow][hs * 64];
        #pragma unroll
        for (int j = 0; j < 16; ++j)
            #pragma unroll
            for (int k = 0; k < 4; ++k) arow[j * 4 + k] = f2bf(v[j][k] * inv);
    }
    __syncthreads();
    int p = t & 127, grp = t >> 7;
    int b0 = grp * 2, b1 = grp * 2 + 1;
    float acc0[8], acc1[8];
    #pragma unroll
    for (int d = 0; d < 8; ++d) { acc0[d] = 0.f; acc1[d] = 0.f; }
    for (int m = 0; m < 32; ++m) {
        float a0 = bf2f(attn[b0 * 32 + m][p]);
        float a1 = bf2f(attn[b1 * 32 + m][p]);
        const float* vbp = (m < 4 ? vproj + (long)m * DVc * NP : vbuf + (long)(m - 4) * DVc * NP)
                           + (long)(dq * 8) * NP + p0 + p;
        #pragma unroll
        for (int d = 0; d < 8; ++d) {
            float vv = vbp[(long)d * NP];
            acc0[d] += a0 * vv;
            acc1[d] += a1 * vv;
        }
    }
    #pragma unroll
    for (int d = 0; d < 8; ++d) {
        long i0 = ((long)b0 * DVc + dq * 8 + d) * NP + p0 + p;
        out[i0] = fm[i0] + 0.5f * acc0[d];
        long i1 = ((long)b1 * DVc + dq * 8 + d) * NP + p0 + p;
        out[i1] = fm[i1] + 0.5f * acc1[d];
    }
}

extern "C" void kernel_launch(void* const* d_in, const int* in_sizes, int n_in,
                              void* d_out, int out_size, void* d_ws, size_t ws_size,
                              hipStream_t stream) {
    const float* fc = (const float*)d_in[0];
    const float* fm = (const float*)d_in[1];
    const float* kb = (const float*)d_in[2];
    const float* vb = (const float*)d_in[3];
    const float* Q  = (const float*)d_in[4];
    const float* K  = (const float*)d_in[5];
    const float* V  = (const float*)d_in[6];
    float* out = (float*)d_out;
    char* ws = (char*)d_ws;
    // workspace layout (bytes)
    unsigned short* fcT   = (unsigned short*)(ws);                 // 4*4096*256*2 = 8388608
    unsigned short* WTq   = (unsigned short*)(ws + 8388608);       // 131072
    unsigned short* WTk   = (unsigned short*)(ws + 8519680);       // 131072
    unsigned short* qT    = (unsigned short*)(ws + 8650752);       // 8388608
    float*          kproj = (float*)(ws + 17039360);               // 16777216
    float*          vproj = (float*)(ws + 33816576);               // 2097152
    float*          scores= (float*)(ws + 35913728);               // 2097152
    float scale = (float)(log(135168.0) / log(1000.0) / 16.0);

    hipLaunchKernelGGL(k_transpose_bf16, dim3(64, 4, 4), dim3(256), 0, stream,
                       fc, fcT, 256, 4096, (long)256 * 4096);
    hipLaunchKernelGGL(k_transpose_bf16, dim3(4, 4, 1), dim3(256), 0, stream,
                       Q, WTq, 256, 256, (long)0);
    hipLaunchKernelGGL(k_transpose_bf16, dim3(4, 4, 1), dim3(256), 0, stream,
                       K, WTk, 256, 256, (long)0);
    hipLaunchKernelGGL(k_vproj, dim3(16, 4), dim3(256), 0, stream, fm, V, vproj);
    hipLaunchKernelGGL(k_proj_gemm, dim3(64, 4, 8), dim3(256), 0, stream,
                       WTq, WTk, fcT, qT, kproj);
    hipLaunchKernelGGL(k_scores, dim3(128, 2), dim3(512), 0, stream,
                       qT, kproj, kb, scores, scale);
    hipLaunchKernelGGL(k_out, dim3(32, 4), dim3(256), 0, stream,
                       scores, vproj, vb, fm, out);
}